// Round 1
// baseline (1597.208 us; speedup 1.0000x reference)
//
#include <hip/hip_runtime.h>
#include <stdint.h>

#define IGNORE_INDEX (-100)

typedef __attribute__((ext_vector_type(8))) short bf16x8;
typedef __attribute__((ext_vector_type(4))) float f32x4;

static constexpr int Bv = 4, Sv = 2048, Dv = 2048, Vv = 32000;
static constexpr int Nv = Bv * (Sv - 1);   // 8188 valid rows
static constexpr int NP = 8192;            // padded row count
static constexpr int BM = 256;             // block tile (rows and cols)
static constexpr int BK = 64;              // K-step
static constexpr int NT = Dv / BK;         // 32 K-tiles

typedef const __attribute__((address_space(1))) unsigned int* gptr_t;
typedef __attribute__((address_space(3))) unsigned int* lptr_t;

__device__ __forceinline__ unsigned short f2bf(float f) {
    unsigned int u = __float_as_uint(f);
    u += 0x7fffu + ((u >> 16) & 1u);   // round-to-nearest-even
    return (unsigned short)(u >> 16);
}

// ---- fp32 -> bf16 for lm_head_weight [V, D] -------------------------------
__global__ void convert_w_kernel(const float* __restrict__ w,
                                 unsigned short* __restrict__ wbf) {
    int i = blockIdx.x * blockDim.x + threadIdx.x;   // one float4
    const float4 v = ((const float4*)w)[i];
    ushort4 o;
    o.x = f2bf(v.x); o.y = f2bf(v.y); o.z = f2bf(v.z); o.w = f2bf(v.w);
    ((ushort4*)wbf)[i] = o;
}

// ---- fp32 -> bf16 for shifted hidden states, rows padded to 8192 ----------
__global__ void convert_h_kernel(const float* __restrict__ h,
                                 unsigned short* __restrict__ hbf) {
    int i = blockIdx.x * blockDim.x + threadIdx.x;   // one float4
    int e0 = i * 4;
    int n = e0 >> 11;       // / 2048
    int d = e0 & 2047;
    ushort4 o;
    if (n < Nv) {
        int b = n / 2047;            // batch
        int s = n - b * 2047;        // position 0..2046
        const float4 v = *(const float4*)(h + ((size_t)b * Sv + s) * Dv + d);
        o.x = f2bf(v.x); o.y = f2bf(v.y); o.z = f2bf(v.z); o.w = f2bf(v.w);
    } else {
        o.x = 0; o.y = 0; o.z = 0; o.w = 0;
    }
    ((ushort4*)hbf)[i] = o;
}

// ---- shifted labels + zero-init of accumulators ---------------------------
__global__ void prep_meta_kernel(const int* __restrict__ labels,
                                 int* __restrict__ t,
                                 float* __restrict__ sumexp,
                                 float* __restrict__ gold) {
    int n = blockIdx.x * blockDim.x + threadIdx.x;
    if (n >= NP) return;
    sumexp[n] = 0.0f;
    gold[n] = 0.0f;
    int tv = IGNORE_INDEX;
    if (n < Nv) {
        int b = n / 2047;
        int s = n - b * 2047;
        tv = labels[b * Sv + s + 1];   // causal shift
    }
    t[n] = tv;
}

// ---- fused GEMM + exp-reduce + gold gather --------------------------------
// 256x256 tile, 8 waves (2M x 4N), per-wave 128x64 output, BK=64.
// Double-buffered LDS (2 x (A 32K + B 32K) = 128 KiB) with depth-2
// counted-vmcnt pipeline: stage K(t+2) while K(t+1) is already in flight;
// s_waitcnt vmcnt(8) waits only the previous tile's 8 loads (T3+T4).
// LDS XOR-swizzle (chunk ^= row&7) realized on the PRODUCER side via the
// per-lane global source address, since global_load_lds dest is linear.
__global__ __launch_bounds__(512, 2)
void ce_gemm(const unsigned short* __restrict__ hbf,
             const unsigned short* __restrict__ wbf,
             const int* __restrict__ t,
             float* __restrict__ sumexp,
             float* __restrict__ gold) {
    __shared__ unsigned short lds_a[2][BM * BK];   // 2 x 32 KiB
    __shared__ unsigned short lds_b[2][BM * BK];   // 2 x 32 KiB
    __shared__ float lds_rowsum[BM];
    __shared__ int lds_t[BM];

    const int tid  = threadIdx.x;
    const int lane = tid & 63;
    const int wave = tid >> 6;      // 0..7
    const int wr   = wave >> 2;     // 0..1  (row half: 128 rows)
    const int wc   = wave & 3;      // 0..3  (col quarter: 64 cols)
    const int quad = lane >> 4;
    const int l15  = lane & 15;
    const int R0   = blockIdx.x * BM;
    const int C0   = blockIdx.y * BM;

    f32x4 acc[8][4];
    const f32x4 z = {0.f, 0.f, 0.f, 0.f};
#pragma unroll
    for (int mi = 0; mi < 8; ++mi)
#pragma unroll
        for (int ni = 0; ni < 4; ++ni)
            acc[mi][ni] = z;

    // staging: thread tid owns LDS chunk (row = tid>>3, jl = tid&7);
    // fetches global chunk jg = jl ^ (row & 7)  -> swizzled LDS layout.
    // 4 instructions per matrix per K-tile, row advancing by 64 each
    // (row&7 unchanged -> same swizzle), 8 loads/thread/K-tile total.
    const int ld_r = tid >> 3;                       // 0..63
    const int jg   = (tid & 7) ^ (ld_r & 7);
    const unsigned short* ga = hbf + (size_t)(R0 + ld_r) * Dv + jg * 8;
    const unsigned short* gb = wbf + (size_t)(C0 + ld_r) * Dv + jg * 8;

#define STAGE(kt, buf)                                                         \
    do {                                                                       \
        const int _k0 = (kt) * BK;                                             \
        unsigned short* _la = &lds_a[(buf)][tid * 8];                          \
        unsigned short* _lb = &lds_b[(buf)][tid * 8];                          \
        _Pragma("unroll")                                                      \
        for (int _i = 0; _i < 4; ++_i) {                                       \
            __builtin_amdgcn_global_load_lds(                                  \
                (gptr_t)(ga + (size_t)_i * 64 * Dv + _k0),                     \
                (lptr_t)(_la + _i * 4096), 16, 0, 0);                          \
            __builtin_amdgcn_global_load_lds(                                  \
                (gptr_t)(gb + (size_t)_i * 64 * Dv + _k0),                     \
                (lptr_t)(_lb + _i * 4096), 16, 0, 0);                          \
        }                                                                      \
    } while (0)

    // prologue: K0 -> buf0, K1 -> buf1; wait K0 only (K1 stays in flight)
    STAGE(0, 0);
    STAGE(1, 1);
    asm volatile("s_waitcnt vmcnt(8)" ::: "memory");
    __builtin_amdgcn_s_barrier();

    int cur = 0;
    for (int kt = 0; kt < NT; ++kt) {
        const unsigned short* ba = &lds_a[cur][0];
        const unsigned short* bb = &lds_b[cur][0];

        // B fragments: 8 reads, reused across all 8 mi
        bf16x8 bfr[4][2];
#pragma unroll
        for (int ni = 0; ni < 4; ++ni) {
            const int brow = wc * 64 + ni * 16 + l15;
            const int sw = brow & 7;
            bfr[ni][0] = *(const bf16x8*)(bb + brow * BK + ((quad ^ sw) * 8));
            bfr[ni][1] = *(const bf16x8*)(bb + brow * BK + (((quad + 4) ^ sw) * 8));
        }

        __builtin_amdgcn_s_setprio(1);
#pragma unroll
        for (int mi = 0; mi < 8; ++mi) {
            const int arow = wr * 128 + mi * 16 + l15;
            const int sw = arow & 7;
            bf16x8 a0 = *(const bf16x8*)(ba + arow * BK + ((quad ^ sw) * 8));
            bf16x8 a1 = *(const bf16x8*)(ba + arow * BK + (((quad + 4) ^ sw) * 8));
#pragma unroll
            for (int ni = 0; ni < 4; ++ni)
                acc[mi][ni] = __builtin_amdgcn_mfma_f32_16x16x32_bf16(
                    a0, bfr[ni][0], acc[mi][ni], 0, 0, 0);
#pragma unroll
            for (int ni = 0; ni < 4; ++ni)
                acc[mi][ni] = __builtin_amdgcn_mfma_f32_16x16x32_bf16(
                    a1, bfr[ni][1], acc[mi][ni], 0, 0, 0);
        }
        __builtin_amdgcn_s_setprio(0);

        // all waves done reading buf[cur] -> safe to overwrite it
        asm volatile("s_waitcnt lgkmcnt(0)" ::: "memory");
        __builtin_amdgcn_s_barrier();

        if (kt + 2 < NT) {
            STAGE(kt + 2, cur);                              // 8 new loads
            asm volatile("s_waitcnt vmcnt(8)" ::: "memory"); // K(t+1) done
        } else if (kt + 1 < NT) {
            asm volatile("s_waitcnt vmcnt(0)" ::: "memory"); // tail drain
        }
        __builtin_amdgcn_s_barrier();
        cur ^= 1;
    }
#undef STAGE

    // ---- fused epilogue: exp + row-sum + gold capture ----
    __syncthreads();
    if (tid < BM) {
        lds_rowsum[tid] = 0.0f;
        lds_t[tid] = t[R0 + tid];
    }
    __syncthreads();

#pragma unroll
    for (int mi = 0; mi < 8; ++mi) {
#pragma unroll
        for (int reg = 0; reg < 4; ++reg) {
            const int lrow = wr * 128 + mi * 16 + quad * 4 + reg;  // C/D row
            const int grow = R0 + lrow;
            const int lbl  = lds_t[lrow];
            float s = 0.0f;
#pragma unroll
            for (int ni = 0; ni < 4; ++ni) {
                const float v = acc[mi][ni][reg];
                s += __expf(v);
                const int gcol = C0 + wc * 64 + ni * 16 + l15;     // C/D col
                if (lbl == gcol) gold[grow] = v;                    // unique writer
            }
            // reduce across the 16 column-lanes sharing this row
#pragma unroll
            for (int off = 1; off < 16; off <<= 1)
                s += __shfl_xor(s, off, 64);
            if (l15 == 0) atomicAdd(&lds_rowsum[lrow], s);
        }
    }
    __syncthreads();
    if (tid < BM) {
        const int grow = R0 + tid;
        if (grow < Nv) atomicAdd(&sumexp[grow], lds_rowsum[tid]);
    }
}

// ---- final scalar: mean over valid rows of log(sumexp) - gold -------------
__global__ void ce_finalize(const float* __restrict__ sumexp,
                            const float* __restrict__ gold,
                            const int* __restrict__ t,
                            float* __restrict__ out) {
    __shared__ float ssum[4];
    __shared__ float scnt[4];
    float s = 0.0f, cnt = 0.0f;
    for (int n = threadIdx.x; n < Nv; n += 256) {
        if (t[n] != IGNORE_INDEX) {
            s += logf(sumexp[n]) - gold[n];
            cnt += 1.0f;
        }
    }
#pragma unroll
    for (int off = 32; off > 0; off >>= 1) {
        s += __shfl_down(s, off, 64);
        cnt += __shfl_down(cnt, off, 64);
    }
    const int wid = threadIdx.x >> 6;
    if ((threadIdx.x & 63) == 0) { ssum[wid] = s; scnt[wid] = cnt; }
    __syncthreads();
    if (threadIdx.x == 0) {
        float S = 0.0f, C = 0.0f;
        for (int i = 0; i < 4; ++i) { S += ssum[i]; C += scnt[i]; }
        out[0] = S / fmaxf(C, 1.0f);
    }
}

extern "C" void kernel_launch(void* const* d_in, const int* in_sizes, int n_in,
                              void* d_out, int out_size, void* d_ws, size_t ws_size,
                              hipStream_t stream) {
    const float* h      = (const float*)d_in[0];   // [4, 2048, 2048] fp32
    const float* w      = (const float*)d_in[1];   // [32000, 2048] fp32
    const int*   labels = (const int*)d_in[2];     // [4, 2048] int
    float* out = (float*)d_out;

    char* ws = (char*)d_ws;
    unsigned short* hbf = (unsigned short*)ws;                                   // 33.6 MB
    unsigned short* wbf = (unsigned short*)(ws + (size_t)NP * Dv * 2);           // 131 MB
    char* tail = ws + (size_t)NP * Dv * 2 + (size_t)Vv * Dv * 2;
    float* sumexp = (float*)tail;
    float* gold   = (float*)(tail + (size_t)NP * 4);
    int*   t      = (int*)(tail + (size_t)NP * 8);

    hipLaunchKernelGGL(convert_w_kernel, dim3((Vv * Dv / 4) / 256), dim3(256), 0, stream, w, wbf);
    hipLaunchKernelGGL(convert_h_kernel, dim3((NP * Dv / 4) / 256), dim3(256), 0, stream, h, hbf);
    hipLaunchKernelGGL(prep_meta_kernel, dim3(NP / 256), dim3(256), 0, stream, labels, t, sumexp, gold);
    hipLaunchKernelGGL(ce_gemm, dim3(NP / BM, Vv / BM), dim3(512), 0, stream,
                       hbf, wbf, t, sumexp, gold);
    hipLaunchKernelGGL(ce_finalize, dim3(1), dim3(256), 0, stream, sumexp, gold, t, out);
}

// Round 2
// 1392.496 us; speedup vs baseline: 1.1470x; 1.1470x over previous
//
#include <hip/hip_runtime.h>
#include <stdint.h>

#define IGNORE_INDEX (-100)

typedef __attribute__((ext_vector_type(8))) short bf16x8;
typedef __attribute__((ext_vector_type(4))) float f32x4;

static constexpr int Bv = 4, Sv = 2048, Dv = 2048, Vv = 32000;
static constexpr int Nv = Bv * (Sv - 1);   // 8188 valid rows
static constexpr int NP = 8192;            // padded row count
static constexpr int BM = 256;             // block tile (rows and cols)
static constexpr int BK = 64;              // K-step
static constexpr int NT = Dv / BK;         // 32 K-tiles (16 iterations x 2)

typedef const __attribute__((address_space(1))) unsigned int* gptr_t;
typedef __attribute__((address_space(3))) unsigned int* lptr_t;

__device__ __forceinline__ unsigned short f2bf(float f) {
    unsigned int u = __float_as_uint(f);
    u += 0x7fffu + ((u >> 16) & 1u);   // round-to-nearest-even
    return (unsigned short)(u >> 16);
}

// ---- fp32 -> bf16 for lm_head_weight [V, D] -------------------------------
__global__ void convert_w_kernel(const float* __restrict__ w,
                                 unsigned short* __restrict__ wbf) {
    int i = blockIdx.x * blockDim.x + threadIdx.x;   // one float4
    const float4 v = ((const float4*)w)[i];
    ushort4 o;
    o.x = f2bf(v.x); o.y = f2bf(v.y); o.z = f2bf(v.z); o.w = f2bf(v.w);
    ((ushort4*)wbf)[i] = o;
}

// ---- fp32 -> bf16 for shifted hidden states, rows padded to 8192 ----------
__global__ void convert_h_kernel(const float* __restrict__ h,
                                 unsigned short* __restrict__ hbf) {
    int i = blockIdx.x * blockDim.x + threadIdx.x;   // one float4
    int e0 = i * 4;
    int n = e0 >> 11;       // / 2048
    int d = e0 & 2047;
    ushort4 o;
    if (n < Nv) {
        int b = n / 2047;            // batch
        int s = n - b * 2047;        // position 0..2046
        const float4 v = *(const float4*)(h + ((size_t)b * Sv + s) * Dv + d);
        o.x = f2bf(v.x); o.y = f2bf(v.y); o.z = f2bf(v.z); o.w = f2bf(v.w);
    } else {
        o.x = 0; o.y = 0; o.z = 0; o.w = 0;
    }
    ((ushort4*)hbf)[i] = o;
}

// ---- shifted labels + zero-init of accumulators ---------------------------
__global__ void prep_meta_kernel(const int* __restrict__ labels,
                                 int* __restrict__ t,
                                 float* __restrict__ sumexp,
                                 float* __restrict__ gold) {
    int n = blockIdx.x * blockDim.x + threadIdx.x;
    if (n >= NP) return;
    sumexp[n] = 0.0f;
    gold[n] = 0.0f;
    int tv = IGNORE_INDEX;
    if (n < Nv) {
        int b = n / 2047;
        int s = n - b * 2047;
        tv = labels[b * Sv + s + 1];   // causal shift
    }
    t[n] = tv;
}

// ---- fused GEMM + exp-reduce + gold gather --------------------------------
// m201-style 8-phase schedule: 256x256 tile, BK=64, 8 waves (2M x 4N).
// Wave row-interleave: wave wr's mi-th fragment rows = mi*32 + wr*16, so the
// 4 quadrant-phases of a K-tile consume A-half0,half0,half1,half1 in order,
// freeing each half-buffer early enough to stage ONE half-tile per phase
// with 3 half-tiles in flight (vmcnt(6) at phases 4/8 only; never 0).
// Buffers fixed: even K-tiles -> buf0, odd -> buf1.
// Stage map (iter j): ph1: A1.h1<-t(2j+1); ph2..5: B0.h0,B0.h1,A0.h0,A0.h1
// <-t(2j+2); ph6..8: B1.h0,B1.h1,A1.h0<-t(2j+3). Last iteration peeled.
// LDS XOR-swizzle (chunk ^= row&7) on the PRODUCER side (global src perm).
__global__ __launch_bounds__(512, 2)
void ce_gemm(const unsigned short* __restrict__ hbf,
             const unsigned short* __restrict__ wbf,
             const int* __restrict__ t,
             float* __restrict__ sumexp,
             float* __restrict__ gold) {
    __shared__ unsigned short lds_a[2][BM * BK];   // 2 x 32 KiB
    __shared__ unsigned short lds_b[2][BM * BK];   // 2 x 32 KiB
    __shared__ float lds_rowsum[BM];
    __shared__ int lds_t[BM];

    const int tid  = threadIdx.x;
    const int lane = tid & 63;
    const int wave = tid >> 6;      // 0..7
    const int wr   = wave >> 2;     // 0..1
    const int wc   = wave & 3;      // 0..3
    const int quad = lane >> 4;
    const int l15  = lane & 15;
    const int R0   = blockIdx.x * BM;
    const int C0   = blockIdx.y * BM;

    f32x4 acc[8][4];
    const f32x4 z = {0.f, 0.f, 0.f, 0.f};
#pragma unroll
    for (int mi = 0; mi < 8; ++mi)
#pragma unroll
        for (int ni = 0; ni < 4; ++ni)
            acc[mi][ni] = z;

    // staging: thread tid owns LDS chunk (row = tid>>3, jl = tid&7);
    // fetches global chunk jg = jl ^ (row & 7) -> swizzled LDS layout.
    const int ld_r = tid >> 3;                       // 0..63
    const int jg   = (tid & 7) ^ (ld_r & 7);
    const unsigned short* ga = hbf + (size_t)(R0 + ld_r) * Dv + jg * 8;
    const unsigned short* gb = wbf + (size_t)(C0 + ld_r) * Dv + jg * 8;

// stage one half (H=0: rows 0..127, H=1: rows 128..255) of one matrix
#define STAGE_HALF(DSTARR, GBASE, KT, H)                                    \
    do {                                                                    \
        _Pragma("unroll")                                                   \
        for (int _i = 2 * (H); _i < 2 * (H) + 2; ++_i) {                    \
            __builtin_amdgcn_global_load_lds(                               \
                (gptr_t)((GBASE) + (size_t)_i * 64 * Dv + (KT) * BK),       \
                (lptr_t)(&DSTARR[tid * 8 + _i * 4096]), 16, 0, 0);          \
        }                                                                   \
    } while (0)

// swizzled LDS fragment read: logical 8-elem chunk C of row R
#define LDSF(BASE, R, C) \
    (*(const bf16x8*)((BASE) + (R) * BK + (((C) ^ ((R) & 7)) * 8)))

#define VM6 asm volatile("s_waitcnt vmcnt(6)" ::: "memory")
#define VM0 asm volatile("s_waitcnt vmcnt(0)" ::: "memory")
#define NOVM ((void)0)

// One phase: quadrant Q of the K-tile in lds buffer ABUF.
// LOADB!=0: also (re)load the 8 B-fragments from lds_b[BBUF] into bfr.
// Stage statement is __VA_ARGS__; VMW is the counted vmcnt wait (or NOVM).
#define PHASE(ABUF, Q, LOADB, BBUF, VMW, ...)                               \
    do {                                                                    \
        bf16x8 a0_, a1_, a2_, a3_;                                          \
        {                                                                   \
            const int r0_ = (2 * (Q)) * 32 + wr * 16 + l15;                 \
            const int r1_ = (2 * (Q) + 1) * 32 + wr * 16 + l15;             \
            const unsigned short* ab_ = &lds_a[ABUF][0];                    \
            a0_ = LDSF(ab_, r0_, quad);                                     \
            a1_ = LDSF(ab_, r0_, quad + 4);                                 \
            a2_ = LDSF(ab_, r1_, quad);                                     \
            a3_ = LDSF(ab_, r1_, quad + 4);                                 \
        }                                                                   \
        if (LOADB) {                                                        \
            const unsigned short* bb_ = &lds_b[BBUF][0];                    \
            _Pragma("unroll")                                               \
            for (int ni_ = 0; ni_ < 4; ++ni_) {                             \
                const int br_ = wc * 64 + ni_ * 16 + l15;                   \
                bfr[ni_][0] = LDSF(bb_, br_, quad);                         \
                bfr[ni_][1] = LDSF(bb_, br_, quad + 4);                     \
            }                                                               \
        }                                                                   \
        __VA_ARGS__;                                                        \
        __builtin_amdgcn_s_barrier();                                       \
        asm volatile("s_waitcnt lgkmcnt(0)" ::: "memory");                  \
        __builtin_amdgcn_sched_barrier(0);                                  \
        __builtin_amdgcn_s_setprio(1);                                      \
        {                                                                   \
            const int miA_ = 2 * (Q), miB_ = 2 * (Q) + 1;                   \
            _Pragma("unroll")                                               \
            for (int ni_ = 0; ni_ < 4; ++ni_) {                             \
                acc[miA_][ni_] = __builtin_amdgcn_mfma_f32_16x16x32_bf16(   \
                    a0_, bfr[ni_][0], acc[miA_][ni_], 0, 0, 0);             \
                acc[miA_][ni_] = __builtin_amdgcn_mfma_f32_16x16x32_bf16(   \
                    a1_, bfr[ni_][1], acc[miA_][ni_], 0, 0, 0);             \
            }                                                               \
            _Pragma("unroll")                                               \
            for (int ni_ = 0; ni_ < 4; ++ni_) {                             \
                acc[miB_][ni_] = __builtin_amdgcn_mfma_f32_16x16x32_bf16(   \
                    a2_, bfr[ni_][0], acc[miB_][ni_], 0, 0, 0);             \
                acc[miB_][ni_] = __builtin_amdgcn_mfma_f32_16x16x32_bf16(   \
                    a3_, bfr[ni_][1], acc[miB_][ni_], 0, 0, 0);             \
            }                                                               \
        }                                                                   \
        __builtin_amdgcn_s_setprio(0);                                      \
        VMW;                                                                \
        __builtin_amdgcn_s_barrier();                                       \
    } while (0)

    bf16x8 bfr[4][2];

    // ---- prologue: tile0 complete (8 loads) + tile1 partial (6 loads) ----
    STAGE_HALF(lds_a[0], ga, 0, 0);
    STAGE_HALF(lds_a[0], ga, 0, 1);
    STAGE_HALF(lds_b[0], gb, 0, 0);
    STAGE_HALF(lds_b[0], gb, 0, 1);
    STAGE_HALF(lds_b[1], gb, 1, 0);
    STAGE_HALF(lds_b[1], gb, 1, 1);
    STAGE_HALF(lds_a[1], ga, 1, 0);
    VM6;                                   // tile0 landed; tile1's 6 in flight
    __builtin_amdgcn_s_barrier();

    // ---- main loop: iterations 0..14 (tiles 0..29), full stage map ----
#pragma unroll 1
    for (int j = 0; j < 15; ++j) {
        const int t1 = 2 * j + 1, t2 = 2 * j + 2, t3 = 2 * j + 3;
        PHASE(0, 0, 1, 0, NOVM, STAGE_HALF(lds_a[1], ga, t1, 1));
        PHASE(0, 1, 0, 0, NOVM, STAGE_HALF(lds_b[0], gb, t2, 0));
        PHASE(0, 2, 0, 0, NOVM, STAGE_HALF(lds_b[0], gb, t2, 1));
        PHASE(0, 3, 0, 0, VM6,  STAGE_HALF(lds_a[0], ga, t2, 0));
        PHASE(1, 0, 1, 1, NOVM, STAGE_HALF(lds_a[0], ga, t2, 1));
        PHASE(1, 1, 0, 1, NOVM, STAGE_HALF(lds_b[1], gb, t3, 0));
        PHASE(1, 2, 0, 1, NOVM, STAGE_HALF(lds_b[1], gb, t3, 1));
        PHASE(1, 3, 0, 1, VM6,  STAGE_HALF(lds_a[1], ga, t3, 0));
    }
    // ---- peeled last iteration (tiles 30, 31): only ph1 stages ----
    PHASE(0, 0, 1, 0, NOVM, STAGE_HALF(lds_a[1], ga, 31, 1));
    PHASE(0, 1, 0, 0, NOVM, NOVM);
    PHASE(0, 2, 0, 0, NOVM, NOVM);
    PHASE(0, 3, 0, 0, VM0,  NOVM);        // drain: tile31 A.h1 must land
    PHASE(1, 0, 1, 1, NOVM, NOVM);
    PHASE(1, 1, 0, 1, NOVM, NOVM);
    PHASE(1, 2, 0, 1, NOVM, NOVM);
    PHASE(1, 3, 0, 1, NOVM, NOVM);

#undef PHASE
#undef STAGE_HALF

    // ---- fused epilogue: exp + row-sum + gold capture ----
    if (tid < BM) {
        lds_rowsum[tid] = 0.0f;
        lds_t[tid] = t[R0 + tid];
    }
    __syncthreads();

#pragma unroll
    for (int mi = 0; mi < 8; ++mi) {
#pragma unroll
        for (int reg = 0; reg < 4; ++reg) {
            // interleaved row map: wave wr's mi-th block = mi*32 + wr*16
            const int lrow = mi * 32 + wr * 16 + quad * 4 + reg;
            const int grow = R0 + lrow;
            const int lbl  = lds_t[lrow];
            float s = 0.0f;
#pragma unroll
            for (int ni = 0; ni < 4; ++ni) {
                const float v = acc[mi][ni][reg];
                s += __expf(v);
                const int gcol = C0 + wc * 64 + ni * 16 + l15;
                if (lbl == gcol) gold[grow] = v;                // unique writer
            }
#pragma unroll
            for (int off = 1; off < 16; off <<= 1)
                s += __shfl_xor(s, off, 64);
            if (l15 == 0) atomicAdd(&lds_rowsum[lrow], s);
        }
    }
    __syncthreads();
    if (tid < BM) {
        const int grow = R0 + tid;
        if (grow < Nv) atomicAdd(&sumexp[grow], lds_rowsum[tid]);
    }
}

// ---- final scalar: mean over valid rows of log(sumexp) - gold -------------
__global__ void ce_finalize(const float* __restrict__ sumexp,
                            const float* __restrict__ gold,
                            const int* __restrict__ t,
                            float* __restrict__ out) {
    __shared__ float ssum[4];
    __shared__ float scnt[4];
    float s = 0.0f, cnt = 0.0f;
    for (int n = threadIdx.x; n < Nv; n += 256) {
        if (t[n] != IGNORE_INDEX) {
            s += logf(sumexp[n]) - gold[n];
            cnt += 1.0f;
        }
    }
#pragma unroll
    for (int off = 32; off > 0; off >>= 1) {
        s += __shfl_down(s, off, 64);
        cnt += __shfl_down(cnt, off, 64);
    }
    const int wid = threadIdx.x >> 6;
    if ((threadIdx.x & 63) == 0) { ssum[wid] = s; scnt[wid] = cnt; }
    __syncthreads();
    if (threadIdx.x == 0) {
        float S = 0.0f, C = 0.0f;
        for (int i = 0; i < 4; ++i) { S += ssum[i]; C += scnt[i]; }
        out[0] = S / fmaxf(C, 1.0f);
    }
}

extern "C" void kernel_launch(void* const* d_in, const int* in_sizes, int n_in,
                              void* d_out, int out_size, void* d_ws, size_t ws_size,
                              hipStream_t stream) {
    const float* h      = (const float*)d_in[0];   // [4, 2048, 2048] fp32
    const float* w      = (const float*)d_in[1];   // [32000, 2048] fp32
    const int*   labels = (const int*)d_in[2];     // [4, 2048] int
    float* out = (float*)d_out;

    char* ws = (char*)d_ws;
    unsigned short* hbf = (unsigned short*)ws;                                   // 33.6 MB
    unsigned short* wbf = (unsigned short*)(ws + (size_t)NP * Dv * 2);           // 131 MB
    char* tail = ws + (size_t)NP * Dv * 2 + (size_t)Vv * Dv * 2;
    float* sumexp = (float*)tail;
    float* gold   = (float*)(tail + (size_t)NP * 4);
    int*   t      = (int*)(tail + (size_t)NP * 8);

    hipLaunchKernelGGL(convert_w_kernel, dim3((Vv * Dv / 4) / 256), dim3(256), 0, stream, w, wbf);
    hipLaunchKernelGGL(convert_h_kernel, dim3((NP * Dv / 4) / 256), dim3(256), 0, stream, h, hbf);
    hipLaunchKernelGGL(prep_meta_kernel, dim3(NP / 256), dim3(256), 0, stream, labels, t, sumexp, gold);
    hipLaunchKernelGGL(ce_gemm, dim3(NP / BM, Vv / BM), dim3(512), 0, stream,
                       hbf, wbf, t, sumexp, gold);
    hipLaunchKernelGGL(ce_finalize, dim3(1), dim3(256), 0, stream, sumexp, gold, t, out);
}